// Round 6
// baseline (136.725 us; speedup 1.0000x reference)
//
#include <hip/hip_runtime.h>

#define BSZ 8
#define PN  2048
#define CIN 512
#define CAP 2048
#define NW  16

// ws layout (bytes):
//   accum @ 0       : 8 floats (S[4], imb[4]) + int ticket @ accum[8]
//   meta  @ 64      : 24 ints (padded list length per (b,c))
//   sList @ 1024    : 24*2048 floats   (score, list order)
//   roiL  @ 394240  : 24*2048 float4   (roi, list order)
//   (areaL / pbn / pbd / pbp regions unused now)

// ---------------- K1: fc+softmax (blocks 24..1047) | select (0..23) ---------
__global__ __launch_bounds__(256) void k_front(
    const float* __restrict__ inp, const float* __restrict__ fcw,
    const float* __restrict__ fcb, const float* __restrict__ ps,
    const float* __restrict__ labels, const float* __restrict__ rois,
    float* __restrict__ logit, float* __restrict__ accum,
    int* __restrict__ meta, float* __restrict__ sList,
    float4* __restrict__ roiList)
{
  const int t = threadIdx.x;
  if (blockIdx.x >= 24) {
    // ---- fc + softmax: wave-per-row-quad, shuffle reduce (round-0 code) ----
    const int gw   = (((int)blockIdx.x - 24) * 256 + t) >> 6;  // 0..4095
    const int lane = t & 63;
    const int kb   = lane << 2;
    const float4 wa0 = *(const float4*)(fcw + (kb + 0) * 4);
    const float4 wa1 = *(const float4*)(fcw + (kb + 1) * 4);
    const float4 wa2 = *(const float4*)(fcw + (kb + 2) * 4);
    const float4 wa3 = *(const float4*)(fcw + (kb + 3) * 4);
    const float4 wb0 = *(const float4*)(fcw + (256 + kb + 0) * 4);
    const float4 wb1 = *(const float4*)(fcw + (256 + kb + 1) * 4);
    const float4 wb2 = *(const float4*)(fcw + (256 + kb + 2) * 4);
    const float4 wb3 = *(const float4*)(fcw + (256 + kb + 3) * 4);
    const float4 bias = *(const float4*)fcb;
    #pragma unroll
    for (int rr = 0; rr < 4; ++rr) {
      const int r = (gw << 2) + rr;                 // row 0..16383
      const float* row = inp + r * CIN;
      const float4 xa = *(const float4*)(row + kb);
      const float4 xb = *(const float4*)(row + 256 + kb);
      float a0 = xa.x*wa0.x + xa.y*wa1.x + xa.z*wa2.x + xa.w*wa3.x
               + xb.x*wb0.x + xb.y*wb1.x + xb.z*wb2.x + xb.w*wb3.x;
      float a1 = xa.x*wa0.y + xa.y*wa1.y + xa.z*wa2.y + xa.w*wa3.y
               + xb.x*wb0.y + xb.y*wb1.y + xb.z*wb2.y + xb.w*wb3.y;
      float a2 = xa.x*wa0.z + xa.y*wa1.z + xa.z*wa2.z + xa.w*wa3.z
               + xb.x*wb0.z + xb.y*wb1.z + xb.z*wb2.z + xb.w*wb3.z;
      float a3 = xa.x*wa0.w + xa.y*wa1.w + xa.z*wa2.w + xa.w*wa3.w
               + xb.x*wb0.w + xb.y*wb1.w + xb.z*wb2.w + xb.w*wb3.w;
      #pragma unroll
      for (int off = 32; off; off >>= 1) {
        a0 += __shfl_xor(a0, off); a1 += __shfl_xor(a1, off);
        a2 += __shfl_xor(a2, off); a3 += __shfl_xor(a3, off);
      }
      if (lane == 0) {
        a0 += bias.x; a1 += bias.y; a2 += bias.z; a3 += bias.w;
        const float m  = fmaxf(fmaxf(a0, a1), fmaxf(a2, a3));
        const float e0 = expf(a0 - m), e1 = expf(a1 - m);
        const float e2 = expf(a2 - m), e3 = expf(a3 - m);
        const float inv = 1.0f / (e0 + e1 + e2 + e3);
        float4 o; o.x = e0*inv; o.y = e1*inv; o.z = e2*inv; o.w = e3*inv;
        *(float4*)(logit + r * 4) = o;
      }
    }
    return;
  }

  // ---- selection -> compacted per-(b,c) lists (roi, score) ----
  const int bc = blockIdx.x;                        // 0..23
  if (bc == 0 && t < 12) accum[t] = 0.0f;           // zero sums + ticket
  const int b = bc / 3;
  const int c = bc % 3;
  const int j0 = t * 8;

  float sv[8];
  int   flg = 0, cnt = 0;
  float vmax = -1e30f;
  int   jmax = 0;
  #pragma unroll
  for (int m = 0; m < 8; ++m) {
    const float s = ps[(b * PN + j0 + m) * 4 + c];
    sv[m] = s;
    if (s > 0.5f) { flg |= 1 << m; ++cnt; }
    if (s > vmax) { vmax = s; jmax = j0 + m; }      // ascending: > = first
  }

  __shared__ float lv[256];
  __shared__ int   lj[256];
  __shared__ int   pre[256];
  lv[t] = vmax; lj[t] = jmax; pre[t] = cnt;
  __syncthreads();
  for (int off = 128; off > 0; off >>= 1) {         // argmax reduce
    if (t < off) {
      const float v2 = lv[t + off]; const int j2 = lj[t + off];
      if (v2 > lv[t] || (v2 == lv[t] && j2 < lj[t])) { lv[t] = v2; lj[t] = j2; }
    }
    __syncthreads();
  }
  for (int off = 1; off < 256; off <<= 1) {         // inclusive scan
    const int add = (t >= off) ? pre[t - off] : 0;
    __syncthreads();
    pre[t] += add;
    __syncthreads();
  }
  const int  totalTh = pre[255];
  const int  excl    = pre[t] - cnt;
  const int  jArg    = lj[0];
  const bool lab     = labels[b * 4 + c] != 0.0f;
  const int  L    = (!lab) ? 0 : ((totalTh > 1) ? totalTh : 1);
  const int  Lpad = (L + 7) & ~7;

  __shared__ float4 lastRoi;
  __shared__ float  lastS;
  float4* dstR = roiList + bc * CAP;
  float*  dstS = sList   + bc * CAP;
  const float4* rb = ((const float4*)rois) + b * PN;

  if (lab) {
    if (totalTh > 1) {
      int pos = excl;
      #pragma unroll
      for (int m = 0; m < 8; ++m) {
        if (flg & (1 << m)) {
          const float4 r = rb[j0 + m];
          dstR[pos] = r; dstS[pos] = sv[m];
          if (pos == L - 1) { lastRoi = r; lastS = sv[m]; }
          ++pos;
        }
      }
    } else if (t == (jArg >> 3)) {
      const float4 r = rb[jArg];
      dstR[0] = r; dstS[0] = sv[jArg & 7];
      lastRoi = r; lastS = sv[jArg & 7];
    }
  }
  __syncthreads();
  if (t < Lpad - L) { dstR[L + t] = lastRoi; dstS[L + t] = lastS; }
  if (t == 0) meta[bc] = Lpad;
}

// ---------------- K2: full-list IoU argmax + fused loss epilogue ------------
// block = (b, itile64); per c = 0..2 sequentially: stage the FULL list
// (<=32 KB) -> 16-way wave-split j-loop (dual chains, area recomputed from
// the staged roi, exact-tie -> lower position) -> 16-way LDS merge into wave
// 0's registers. Wave 0 then owns the complete per-i result for all 3 c and
// runs the k_back epilogue in-place (no pb* round-trip, no 3rd kernel).
__global__ __launch_bounds__(1024, 4) void k_assign(
    const float* __restrict__ rois, const int* __restrict__ meta,
    const float4* __restrict__ roiList, const float* __restrict__ sList,
    const float* __restrict__ logit, const float* __restrict__ labels,
    float* __restrict__ accum, float* __restrict__ loss)
{
  const int blk  = blockIdx.x;                      // 0..255
  const int t    = threadIdx.x;
  const int lane = t & 63;
  const int wv   = t >> 6;
  const int b    = blk >> 5;
  const int it   = blk & 31;

  __shared__ __align__(16) float4 sroi[2048];       // 32 KB full list
  __shared__ float smn[NW][64];                     // 4 KB
  __shared__ float smd[NW][64];                     // 4 KB
  __shared__ int   smp[NW][64];                     // 4 KB

  const int i = (it << 6) + lane;
  const float4 ri = ((const float4*)rois)[b * PN + i];
  const float areai = (ri.z - ri.x) * (ri.w - ri.y);

  auto upd = [&](float& n, float& d, int& p, const float4 rj, const int pos) {
    const float aj = (rj.z - rj.x) * (rj.w - rj.y); // == sel's expression
    const float lx = fmaxf(ri.x, rj.x), ly = fmaxf(ri.y, rj.y);
    const float rx = fminf(ri.z, rj.z), ry = fminf(ri.w, rj.w);
    const float ww = fmaxf(rx - lx, 0.0f), hh = fmaxf(ry - ly, 0.0f);
    const float inter = ww * hh;
    const float uni   = areai + aj - inter;         // >= 1 always
    if (inter * d > n * uni) { n = inter; d = uni; p = pos; }
  };

  float BNf[3], BDf[3]; int BPf[3];                 // final (valid in wv 0)

  for (int c = 0; c < 3; ++c) {
    const int cnt = meta[b * 3 + c];                // padded, mult of 8, <=2048
    const float4* src = roiList + (b * 3 + c) * CAP;
    if (t < cnt)        sroi[t]        = src[t];    // coalesced full-list stage
    if (t + 1024 < cnt) sroi[t + 1024] = src[t + 1024];
    __syncthreads();                                // B1: staged

    const int C  = (((cnt + 15) >> 4) + 7) & ~7;    // per-wave chunk, mult 8
    const int g0 = wv * C;
    int g1 = g0 + C; if (g1 > cnt) g1 = cnt;
    float nA = -2.0f, dA = 1.0f, nB = -2.0f, dB = 1.0f;
    int   pA = 0, pB = 0;
    for (int g = g0; g < g1; g += 4) {              // cnt mult of 8 -> exact
      const float4 r0 = sroi[g],     r1 = sroi[g + 1];
      const float4 r2 = sroi[g + 2], r3 = sroi[g + 3];
      upd(nA, dA, pA, r0, g);                       // chain A: g, g+1
      upd(nB, dB, pB, r2, g + 2);                   // chain B: g+2, g+3
      upd(nA, dA, pA, r1, g + 1);
      upd(nB, dB, pB, r3, g + 3);
    }
    // merge B into A; exact tie -> lower position (ref = first max)
    const float tB = nB * dA, tA = nA * dB;
    if (tB > tA || (tB == tA && pB < pA)) { nA = nB; dA = dB; pA = pB; }

    smn[wv][lane] = nA; smd[wv][lane] = dA; smp[wv][lane] = pA;
    __syncthreads();                                // B2: partials ready
    if (wv == 0) {
      float bn = nA, bd = dA; int bp = pA;          // wv0 = lowest positions
      #pragma unroll 1
      for (int w2 = 1; w2 < NW; ++w2) {             // wv-ascending: > = first
        const float n = smn[w2][lane];
        const float d = smd[w2][lane];
        const int   p = smp[w2][lane];
        if (n * bd > bn * d) { bn = n; bd = d; bp = p; }
      }
      BNf[c] = bn; BDf[c] = bd; BPf[c] = bp;
    }
    __syncthreads();                                // B3: scratch+sroi reusable
  }

  if (wv != 0) return;                              // epilogue is wave 0 only

  // ---- epilogue for this block's 64 i (lane <-> i), k_back math verbatim ----
  const int gi = b * PN + i;
  float v[3], sc[3];
  #pragma unroll
  for (int c = 0; c < 3; ++c) {
    v[c]  = BNf[c] / BDf[c];                        // exact IEEE divide
    sc[c] = sList[(b * 3 + c) * CAP + BPf[c]];
  }
  float runI = -1.0f, runw = 1.0f;
  if (v[0] > runI) { runw = sc[0]; runI = v[0]; }
  if (v[1] > runI) { runw = sc[1]; runI = v[1]; }
  if (v[2] > runI) { runw = sc[2]; runI = v[2]; }
  const float y0 = (v[0] > 0.5f) ? 1.0f : 0.0f;
  const float y1 = (v[1] > 0.5f) ? 1.0f : 0.0f;
  const float y2 = (v[2] > 0.5f) ? 1.0f : 0.0f;
  const float y3 = (y0 + y1 + y2 == 0.0f) ? 1.0f : 0.0f;

  const float4 lg = ((const float4*)logit)[gi];
  const float lb0 = labels[b * 4 + 0];
  const float lb1 = labels[b * 4 + 1];
  const float lb2 = labels[b * 4 + 2];

  auto term = [&](const float l, const float yv, const float labv) -> float {
    const float p  = fminf(fmaxf(l, 1e-7f), 1.0f - 1e-7f);
    const float om = 1.0f - p;
    const float fl = -yv * logf(p) * om * om;       // focal, gamma=2
    const float wl = 10.0f * expf(l) * (1.0f - labv) + labv;
    return runw * fl * wl;                          // /imb deferred
  };
  float s[8];
  s[0] = term(lg.x, y0, lb0); s[1] = term(lg.y, y1, lb1);
  s[2] = term(lg.z, y2, lb2); s[3] = term(lg.w, y3, 1.0f);
  s[4] = y0; s[5] = y1; s[6] = y2; s[7] = y3;

  #pragma unroll
  for (int k = 0; k < 8; ++k)
    #pragma unroll
    for (int off = 32; off; off >>= 1) s[k] += __shfl_xor(s[k], off);

  if (lane == 0) {
    #pragma unroll
    for (int k = 0; k < 8; ++k) atomicAdd(&accum[k], s[k]);
    __threadfence();
    const int ticket = __hip_atomic_fetch_add((int*)(accum + 8), 1,
                        __ATOMIC_ACQ_REL, __HIP_MEMORY_SCOPE_AGENT);
    if (ticket == 255) {                            // last block finalizes
      float L = 0.0f;
      #pragma unroll
      for (int c = 0; c < 4; ++c) {
        const float num = __hip_atomic_load(accum + c,
                            __ATOMIC_RELAXED, __HIP_MEMORY_SCOPE_AGENT);
        const float den = __hip_atomic_load(accum + 4 + c,
                            __ATOMIC_RELAXED, __HIP_MEMORY_SCOPE_AGENT);
        L += num / (den + 1e-7f);
      }
      loss[0] = L * 0.125f;                         // / bs, exact (pow2)
    }
  }
}

extern "C" void kernel_launch(void* const* d_in, const int* in_sizes, int n_in,
                              void* d_out, int out_size, void* d_ws, size_t ws_size,
                              hipStream_t stream)
{
  (void)in_sizes; (void)n_in; (void)out_size; (void)ws_size;
  const float* inp    = (const float*)d_in[0];
  const float* fcw    = (const float*)d_in[1];
  const float* fcb    = (const float*)d_in[2];
  const float* ps     = (const float*)d_in[3];
  const float* labels = (const float*)d_in[4];
  const float* rois   = (const float*)d_in[5];
  float* out = (float*)d_out;                       // 65536 logit + 1 loss

  char* ws = (char*)d_ws;
  float*  accum   = (float*) (ws);
  int*    meta    = (int*)   (ws + 64);
  float*  sList   = (float*) (ws + 1024);
  float4* roiL    = (float4*)(ws + 394240);

  k_front <<<1048, 256,  0, stream>>>(inp, fcw, fcb, ps, labels, rois,
                                      out, accum, meta, sList, roiL);
  k_assign<<<256,  1024, 0, stream>>>(rois, meta, roiL, sList, out, labels,
                                      accum, out + BSZ * PN * 4);
}

// Round 7
// 133.683 us; speedup vs baseline: 1.0228x; 1.0228x over previous
//
#include <hip/hip_runtime.h>

#define BSZ 8
#define PN  2048
#define CIN 512
#define CAP 2048

// ws layout (bytes):
//   accum @ 0       : 8 floats (S[4], imb[4]) + int ticket @ accum[8]
//   meta  @ 64      : 24 ints (padded list length per (b,c))
//   sList @ 1024    : 24*2048 floats   (score, list order)
//   roiL  @ 394240  : 24*2048 float4   (roi, list order)

// ---------------- K1: fc+softmax (blocks 24..1047) | select (0..23) ---------
__global__ __launch_bounds__(256) void k_front(
    const float* __restrict__ inp, const float* __restrict__ fcw,
    const float* __restrict__ fcb, const float* __restrict__ ps,
    const float* __restrict__ labels, const float* __restrict__ rois,
    float* __restrict__ logit, float* __restrict__ accum,
    int* __restrict__ meta, float* __restrict__ sList,
    float4* __restrict__ roiList)
{
  const int t = threadIdx.x;
  if (blockIdx.x >= 24) {
    // ---- fc + softmax: wave-per-row-quad, shuffle reduce (round-0 code) ----
    const int gw   = (((int)blockIdx.x - 24) * 256 + t) >> 6;  // 0..4095
    const int lane = t & 63;
    const int kb   = lane << 2;
    const float4 wa0 = *(const float4*)(fcw + (kb + 0) * 4);
    const float4 wa1 = *(const float4*)(fcw + (kb + 1) * 4);
    const float4 wa2 = *(const float4*)(fcw + (kb + 2) * 4);
    const float4 wa3 = *(const float4*)(fcw + (kb + 3) * 4);
    const float4 wb0 = *(const float4*)(fcw + (256 + kb + 0) * 4);
    const float4 wb1 = *(const float4*)(fcw + (256 + kb + 1) * 4);
    const float4 wb2 = *(const float4*)(fcw + (256 + kb + 2) * 4);
    const float4 wb3 = *(const float4*)(fcw + (256 + kb + 3) * 4);
    const float4 bias = *(const float4*)fcb;
    #pragma unroll
    for (int rr = 0; rr < 4; ++rr) {
      const int r = (gw << 2) + rr;                 // row 0..16383
      const float* row = inp + r * CIN;
      const float4 xa = *(const float4*)(row + kb);
      const float4 xb = *(const float4*)(row + 256 + kb);
      float a0 = xa.x*wa0.x + xa.y*wa1.x + xa.z*wa2.x + xa.w*wa3.x
               + xb.x*wb0.x + xb.y*wb1.x + xb.z*wb2.x + xb.w*wb3.x;
      float a1 = xa.x*wa0.y + xa.y*wa1.y + xa.z*wa2.y + xa.w*wa3.y
               + xb.x*wb0.y + xb.y*wb1.y + xb.z*wb2.y + xb.w*wb3.y;
      float a2 = xa.x*wa0.z + xa.y*wa1.z + xa.z*wa2.z + xa.w*wa3.z
               + xb.x*wb0.z + xb.y*wb1.z + xb.z*wb2.z + xb.w*wb3.z;
      float a3 = xa.x*wa0.w + xa.y*wa1.w + xa.z*wa2.w + xa.w*wa3.w
               + xb.x*wb0.w + xb.y*wb1.w + xb.z*wb2.w + xb.w*wb3.w;
      #pragma unroll
      for (int off = 32; off; off >>= 1) {
        a0 += __shfl_xor(a0, off); a1 += __shfl_xor(a1, off);
        a2 += __shfl_xor(a2, off); a3 += __shfl_xor(a3, off);
      }
      if (lane == 0) {
        a0 += bias.x; a1 += bias.y; a2 += bias.z; a3 += bias.w;
        const float m  = fmaxf(fmaxf(a0, a1), fmaxf(a2, a3));
        const float e0 = expf(a0 - m), e1 = expf(a1 - m);
        const float e2 = expf(a2 - m), e3 = expf(a3 - m);
        const float inv = 1.0f / (e0 + e1 + e2 + e3);
        float4 o; o.x = e0*inv; o.y = e1*inv; o.z = e2*inv; o.w = e3*inv;
        *(float4*)(logit + r * 4) = o;
      }
    }
    return;
  }

  // ---- selection -> compacted per-(b,c) lists (roi, score) ----
  const int bc = blockIdx.x;                        // 0..23
  if (bc == 0 && t < 12) accum[t] = 0.0f;           // zero sums + ticket
  const int b = bc / 3;
  const int c = bc % 3;
  const int j0 = t * 8;

  float sv[8];
  int   flg = 0, cnt = 0;
  float vmax = -1e30f;
  int   jmax = 0;
  #pragma unroll
  for (int m = 0; m < 8; ++m) {
    const float s = ps[(b * PN + j0 + m) * 4 + c];
    sv[m] = s;
    if (s > 0.5f) { flg |= 1 << m; ++cnt; }
    if (s > vmax) { vmax = s; jmax = j0 + m; }      // ascending: > = first
  }

  __shared__ float lv[256];
  __shared__ int   lj[256];
  __shared__ int   pre[256];
  lv[t] = vmax; lj[t] = jmax; pre[t] = cnt;
  __syncthreads();
  for (int off = 128; off > 0; off >>= 1) {         // argmax reduce
    if (t < off) {
      const float v2 = lv[t + off]; const int j2 = lj[t + off];
      if (v2 > lv[t] || (v2 == lv[t] && j2 < lj[t])) { lv[t] = v2; lj[t] = j2; }
    }
    __syncthreads();
  }
  for (int off = 1; off < 256; off <<= 1) {         // inclusive scan
    const int add = (t >= off) ? pre[t - off] : 0;
    __syncthreads();
    pre[t] += add;
    __syncthreads();
  }
  const int  totalTh = pre[255];
  const int  excl    = pre[t] - cnt;
  const int  jArg    = lj[0];
  const bool lab     = labels[b * 4 + c] != 0.0f;
  const int  L    = (!lab) ? 0 : ((totalTh > 1) ? totalTh : 1);
  const int  Lpad = (L + 7) & ~7;

  __shared__ float4 lastRoi;
  __shared__ float  lastS;
  float4* dstR = roiList + bc * CAP;
  float*  dstS = sList   + bc * CAP;
  const float4* rb = ((const float4*)rois) + b * PN;

  if (lab) {
    if (totalTh > 1) {
      int pos = excl;
      #pragma unroll
      for (int m = 0; m < 8; ++m) {
        if (flg & (1 << m)) {
          const float4 r = rb[j0 + m];
          dstR[pos] = r; dstS[pos] = sv[m];
          if (pos == L - 1) { lastRoi = r; lastS = sv[m]; }
          ++pos;
        }
      }
    } else if (t == (jArg >> 3)) {
      const float4 r = rb[jArg];
      dstR[0] = r; dstS[0] = sv[jArg & 7];
      lastRoi = r; lastS = sv[jArg & 7];
    }
  }
  __syncthreads();
  if (t < Lpad - L) { dstR[L + t] = lastRoi; dstS[L + t] = lastS; }
  if (t == 0) meta[bc] = Lpad;
}

// ---------------- K2: full-list IoU argmax + fused epilogue, 4 blocks/CU ----
// 512 blocks x 512 threads (8 waves) = 4 blocks/CU = 32 waves/CU (cap).
// block = (b = blk&7 interleaved, itile32). Lanes 0..31 and 32..63 hold the
// SAME 32 i's but process different j-chunks (16 chunks = 8 waves x 2 halves;
// one ds_read_b128 feeds 2 j x 32 i with 2 distinct addrs = free broadcast).
// Chunks ascend in j; strict-> merge over chunks keeps first-max ties. Wave 0
// merges 16 partials per i and runs the k_back epilogue in-place.
__global__ __launch_bounds__(512, 8) void k_assign(
    const float* __restrict__ rois, const int* __restrict__ meta,
    const float4* __restrict__ roiList, const float* __restrict__ sList,
    const float* __restrict__ logit, const float* __restrict__ labels,
    float* __restrict__ accum, float* __restrict__ loss)
{
  const int blk   = blockIdx.x;                     // 0..511
  const int t     = threadIdx.x;                    // 0..511
  const int lane  = t & 63;
  const int wv    = t >> 6;                         // 0..7
  const int l32   = lane & 31;
  const int chunk = (wv << 1) | (lane >> 5);        // 0..15, ascending in j
  const int b     = blk & 7;                        // interleave b -> balance
  const int it    = blk >> 3;                       // 0..63
  const int i     = (it << 5) + l32;                // this lane's i

  __shared__ __align__(16) char ldsraw[32768];      // 32 KB -> 4 blocks/CU
  float4* sroi = (float4*)ldsraw;                   // [2048] full list
  float*  smn  = (float*)ldsraw;                    // [16][32] aliased post-B2
  float*  smd  = (float*)(ldsraw + 2048);
  int*    smp  = (int*)  (ldsraw + 4096);

  const float4 ri = ((const float4*)rois)[b * PN + i];
  const float areai = (ri.z - ri.x) * (ri.w - ri.y);

  auto upd = [&](float& n, float& d, int& p, const float4 rj, const int pos) {
    const float aj = (rj.z - rj.x) * (rj.w - rj.y); // == sel's expression
    const float lx = fmaxf(ri.x, rj.x), ly = fmaxf(ri.y, rj.y);
    const float rx = fminf(ri.z, rj.z), ry = fminf(ri.w, rj.w);
    const float ww = fmaxf(rx - lx, 0.0f), hh = fmaxf(ry - ly, 0.0f);
    const float inter = ww * hh;
    const float uni   = areai + aj - inter;         // >= 1 always
    if (inter * d > n * uni) { n = inter; d = uni; p = pos; }
  };

  float BNf[3], BDf[3]; int BPf[3];                 // valid in wv0/lane<32

  #pragma unroll
  for (int c = 0; c < 3; ++c) {
    const int cnt = meta[b * 3 + c];                // padded, mult of 8
    const float4* src = roiList + (b * 3 + c) * CAP;
    for (int idx = t; idx < cnt; idx += 512)        // coalesced full stage
      sroi[idx] = src[idx];
    __syncthreads();                                // B1: staged

    const int C  = (((cnt + 15) >> 4) + 7) & ~7;    // per-chunk, mult of 8
    const int g0 = chunk * C;
    int g1 = g0 + C; if (g1 > cnt) g1 = cnt;
    float nA = -2.0f, dA = 1.0f, nB = -2.0f, dB = 1.0f;
    int   pA = 0, pB = 0;
    for (int g = g0; g < g1; g += 4) {              // span mult of 8 -> exact
      const float4 r0 = sroi[g],     r1 = sroi[g + 1];
      const float4 r2 = sroi[g + 2], r3 = sroi[g + 3];
      upd(nA, dA, pA, r0, g);                       // chain A: g, g+1
      upd(nB, dB, pB, r2, g + 2);                   // chain B: g+2, g+3
      upd(nA, dA, pA, r1, g + 1);
      upd(nB, dB, pB, r3, g + 3);
    }
    // merge B into A; exact tie -> lower position (ref = first max)
    const float tB = nB * dA, tA = nA * dB;
    if (tB > tA || (tB == tA && pB < pA)) { nA = nB; dA = dB; pA = pB; }

    __syncthreads();                                // B2: sroi reads done
    smn[chunk * 32 + l32] = nA;
    smd[chunk * 32 + l32] = dA;
    smp[chunk * 32 + l32] = pA;
    __syncthreads();                                // B2b: partials visible
    if (wv == 0 && lane < 32) {                     // lane<32 holds chunk 0
      float bn = nA, bd = dA; int bp = pA;
      for (int k = 1; k < 16; ++k) {                // chunk-ascending: > first
        const float n = smn[k * 32 + l32];
        const float d = smd[k * 32 + l32];
        const int   p = smp[k * 32 + l32];
        if (n * bd > bn * d) { bn = n; bd = d; bp = p; }
      }
      BNf[c] = bn; BDf[c] = bd; BPf[c] = bp;
    }
    __syncthreads();                                // B3: merge reads done
  }

  if (wv != 0) return;                              // epilogue = wave 0 only

  // ---- epilogue for this block's 32 i (lanes 0..31), k_back math verbatim --
  float s[8] = {0.f, 0.f, 0.f, 0.f, 0.f, 0.f, 0.f, 0.f};
  if (lane < 32) {
    const int gi = b * PN + i;
    float v[3], sc[3];
    #pragma unroll
    for (int c = 0; c < 3; ++c) {
      v[c]  = BNf[c] / BDf[c];                      // exact IEEE divide
      sc[c] = sList[(b * 3 + c) * CAP + BPf[c]];
    }
    float runI = -1.0f, runw = 1.0f;
    if (v[0] > runI) { runw = sc[0]; runI = v[0]; }
    if (v[1] > runI) { runw = sc[1]; runI = v[1]; }
    if (v[2] > runI) { runw = sc[2]; runI = v[2]; }
    const float y0 = (v[0] > 0.5f) ? 1.0f : 0.0f;
    const float y1 = (v[1] > 0.5f) ? 1.0f : 0.0f;
    const float y2 = (v[2] > 0.5f) ? 1.0f : 0.0f;
    const float y3 = (y0 + y1 + y2 == 0.0f) ? 1.0f : 0.0f;

    const float4 lg = ((const float4*)logit)[gi];
    const float lb0 = labels[b * 4 + 0];
    const float lb1 = labels[b * 4 + 1];
    const float lb2 = labels[b * 4 + 2];

    auto term = [&](const float l, const float yv, const float labv) -> float {
      const float p  = fminf(fmaxf(l, 1e-7f), 1.0f - 1e-7f);
      const float om = 1.0f - p;
      const float fl = -yv * logf(p) * om * om;     // focal, gamma=2
      const float wl = 10.0f * expf(l) * (1.0f - labv) + labv;
      return runw * fl * wl;                        // /imb deferred
    };
    s[0] = term(lg.x, y0, lb0); s[1] = term(lg.y, y1, lb1);
    s[2] = term(lg.z, y2, lb2); s[3] = term(lg.w, y3, 1.0f);
    s[4] = y0; s[5] = y1; s[6] = y2; s[7] = y3;
  }
  #pragma unroll
  for (int k = 0; k < 8; ++k)
    #pragma unroll
    for (int off = 32; off; off >>= 1) s[k] += __shfl_xor(s[k], off);

  if (lane < 8) atomicAdd(&accum[lane], s[lane]);   // 8 parallel addresses
  __threadfence();                                  // drain adds (per-wave)
  if (lane == 0) {
    const int ticket = __hip_atomic_fetch_add((int*)(accum + 8), 1,
                        __ATOMIC_ACQ_REL, __HIP_MEMORY_SCOPE_AGENT);
    if (ticket == 511) {                            // last block finalizes
      float L = 0.0f;
      #pragma unroll
      for (int c = 0; c < 4; ++c) {
        const float num = __hip_atomic_load(accum + c,
                            __ATOMIC_RELAXED, __HIP_MEMORY_SCOPE_AGENT);
        const float den = __hip_atomic_load(accum + 4 + c,
                            __ATOMIC_RELAXED, __HIP_MEMORY_SCOPE_AGENT);
        L += num / (den + 1e-7f);
      }
      loss[0] = L * 0.125f;                         // / bs, exact (pow2)
    }
  }
}

extern "C" void kernel_launch(void* const* d_in, const int* in_sizes, int n_in,
                              void* d_out, int out_size, void* d_ws, size_t ws_size,
                              hipStream_t stream)
{
  (void)in_sizes; (void)n_in; (void)out_size; (void)ws_size;
  const float* inp    = (const float*)d_in[0];
  const float* fcw    = (const float*)d_in[1];
  const float* fcb    = (const float*)d_in[2];
  const float* ps     = (const float*)d_in[3];
  const float* labels = (const float*)d_in[4];
  const float* rois   = (const float*)d_in[5];
  float* out = (float*)d_out;                       // 65536 logit + 1 loss

  char* ws = (char*)d_ws;
  float*  accum   = (float*) (ws);
  int*    meta    = (int*)   (ws + 64);
  float*  sList   = (float*) (ws + 1024);
  float4* roiL    = (float4*)(ws + 394240);

  k_front <<<1048, 256, 0, stream>>>(inp, fcw, fcb, ps, labels, rois,
                                     out, accum, meta, sList, roiL);
  k_assign<<<512,  512, 0, stream>>>(rois, meta, roiL, sList, out, labels,
                                     accum, out + BSZ * PN * 4);
}

// Round 8
// 117.618 us; speedup vs baseline: 1.1625x; 1.1366x over previous
//
#include <hip/hip_runtime.h>

#define BSZ 8
#define PN  2048
#define CIN 512
#define CAP 2048
#define NW  16

// ws layout (bytes):
//   accum @ 0       : 8 floats (S[4], imb[4]) + int ticket @ accum[8]
//   meta  @ 64      : 24 ints (padded list length per (b,c))
//   sList @ 1024    : 24*2048 floats   (score, list order)
//   roiL  @ 394240  : 24*2048 float4   (roi, list order)
//   pbn   @ 1180672 : 24*2048 floats (best numerator, per (b,c,i))
//   pbd   @ 1573888 : 24*2048 floats (best denominator)
//   pbp   @ 1967104 : 24*2048 ints   (best list position)

// ---------------- K1: fc+softmax (blocks 24..1047) | select (0..23) ---------
__global__ __launch_bounds__(256) void k_front(
    const float* __restrict__ inp, const float* __restrict__ fcw,
    const float* __restrict__ fcb, const float* __restrict__ ps,
    const float* __restrict__ labels, const float* __restrict__ rois,
    float* __restrict__ logit, float* __restrict__ accum,
    int* __restrict__ meta, float* __restrict__ sList,
    float4* __restrict__ roiList)
{
  const int t = threadIdx.x;
  if (blockIdx.x >= 24) {
    // ---- fc + softmax: wave-per-row-quad, shuffle reduce (round-0 code) ----
    const int gw   = (((int)blockIdx.x - 24) * 256 + t) >> 6;  // 0..4095
    const int lane = t & 63;
    const int kb   = lane << 2;
    const float4 wa0 = *(const float4*)(fcw + (kb + 0) * 4);
    const float4 wa1 = *(const float4*)(fcw + (kb + 1) * 4);
    const float4 wa2 = *(const float4*)(fcw + (kb + 2) * 4);
    const float4 wa3 = *(const float4*)(fcw + (kb + 3) * 4);
    const float4 wb0 = *(const float4*)(fcw + (256 + kb + 0) * 4);
    const float4 wb1 = *(const float4*)(fcw + (256 + kb + 1) * 4);
    const float4 wb2 = *(const float4*)(fcw + (256 + kb + 2) * 4);
    const float4 wb3 = *(const float4*)(fcw + (256 + kb + 3) * 4);
    const float4 bias = *(const float4*)fcb;
    #pragma unroll
    for (int rr = 0; rr < 4; ++rr) {
      const int r = (gw << 2) + rr;                 // row 0..16383
      const float* row = inp + r * CIN;
      const float4 xa = *(const float4*)(row + kb);
      const float4 xb = *(const float4*)(row + 256 + kb);
      float a0 = xa.x*wa0.x + xa.y*wa1.x + xa.z*wa2.x + xa.w*wa3.x
               + xb.x*wb0.x + xb.y*wb1.x + xb.z*wb2.x + xb.w*wb3.x;
      float a1 = xa.x*wa0.y + xa.y*wa1.y + xa.z*wa2.y + xa.w*wa3.y
               + xb.x*wb0.y + xb.y*wb1.y + xb.z*wb2.y + xb.w*wb3.y;
      float a2 = xa.x*wa0.z + xa.y*wa1.z + xa.z*wa2.z + xa.w*wa3.z
               + xb.x*wb0.z + xb.y*wb1.z + xb.z*wb2.z + xb.w*wb3.z;
      float a3 = xa.x*wa0.w + xa.y*wa1.w + xa.z*wa2.w + xa.w*wa3.w
               + xb.x*wb0.w + xb.y*wb1.w + xb.z*wb2.w + xb.w*wb3.w;
      #pragma unroll
      for (int off = 32; off; off >>= 1) {
        a0 += __shfl_xor(a0, off); a1 += __shfl_xor(a1, off);
        a2 += __shfl_xor(a2, off); a3 += __shfl_xor(a3, off);
      }
      if (lane == 0) {
        a0 += bias.x; a1 += bias.y; a2 += bias.z; a3 += bias.w;
        const float m  = fmaxf(fmaxf(a0, a1), fmaxf(a2, a3));
        const float e0 = expf(a0 - m), e1 = expf(a1 - m);
        const float e2 = expf(a2 - m), e3 = expf(a3 - m);
        const float inv = 1.0f / (e0 + e1 + e2 + e3);
        float4 o; o.x = e0*inv; o.y = e1*inv; o.z = e2*inv; o.w = e3*inv;
        *(float4*)(logit + r * 4) = o;
      }
    }
    return;
  }

  // ---- selection -> compacted per-(b,c) lists (roi, score) ----
  const int bc = blockIdx.x;                        // 0..23
  if (bc == 0 && t < 12) accum[t] = 0.0f;           // zero sums + ticket
  const int b = bc / 3;
  const int c = bc % 3;
  const int j0 = t * 8;

  float sv[8];
  int   flg = 0, cnt = 0;
  float vmax = -1e30f;
  int   jmax = 0;
  #pragma unroll
  for (int m = 0; m < 8; ++m) {
    const float s = ps[(b * PN + j0 + m) * 4 + c];
    sv[m] = s;
    if (s > 0.5f) { flg |= 1 << m; ++cnt; }
    if (s > vmax) { vmax = s; jmax = j0 + m; }      // ascending: > = first
  }

  __shared__ float lv[256];
  __shared__ int   lj[256];
  __shared__ int   pre[256];
  lv[t] = vmax; lj[t] = jmax; pre[t] = cnt;
  __syncthreads();
  for (int off = 128; off > 0; off >>= 1) {         // argmax reduce
    if (t < off) {
      const float v2 = lv[t + off]; const int j2 = lj[t + off];
      if (v2 > lv[t] || (v2 == lv[t] && j2 < lj[t])) { lv[t] = v2; lj[t] = j2; }
    }
    __syncthreads();
  }
  for (int off = 1; off < 256; off <<= 1) {         // inclusive scan
    const int add = (t >= off) ? pre[t - off] : 0;
    __syncthreads();
    pre[t] += add;
    __syncthreads();
  }
  const int  totalTh = pre[255];
  const int  excl    = pre[t] - cnt;
  const int  jArg    = lj[0];
  const bool lab     = labels[b * 4 + c] != 0.0f;
  const int  L    = (!lab) ? 0 : ((totalTh > 1) ? totalTh : 1);
  const int  Lpad = (L + 7) & ~7;

  __shared__ float4 lastRoi;
  __shared__ float  lastS;
  float4* dstR = roiList + bc * CAP;
  float*  dstS = sList   + bc * CAP;
  const float4* rb = ((const float4*)rois) + b * PN;

  if (lab) {
    if (totalTh > 1) {
      int pos = excl;
      #pragma unroll
      for (int m = 0; m < 8; ++m) {
        if (flg & (1 << m)) {
          const float4 r = rb[j0 + m];
          dstR[pos] = r; dstS[pos] = sv[m];
          if (pos == L - 1) { lastRoi = r; lastS = sv[m]; }
          ++pos;
        }
      }
    } else if (t == (jArg >> 3)) {
      const float4 r = rb[jArg];
      dstR[0] = r; dstS[0] = sv[jArg & 7];
      lastRoi = r; lastS = sv[jArg & 7];
    }
  }
  __syncthreads();
  if (t < Lpad - L) { dstR[L + t] = lastRoi; dstS[L + t] = lastS; }
  if (t == 0) meta[bc] = Lpad;
}

// ---------------- K2: per-(b,c) IoU argmax, load-balanced -------------------
// block = (bc, itile64): ONE class list per block -> every non-empty block is
// ~uniform (cnt ~ 1024 +- 3%) and empty blocks retire instantly. 768 blocks >
// 512 residency slots -> dynamic refill fixes the per-b load imbalance that
// capped R6/R7 at 20% time-avg occupancy. 16 waves split j 16-ways; all 64
// lanes of a wave read the SAME sroi[g] (uniform broadcast, conflict-free);
// area recomputed in-VALU. Result per (i,c) is final -> pb*, merged by k_back.
__global__ __launch_bounds__(1024, 8) void k_assign(
    const float* __restrict__ rois, const int* __restrict__ meta,
    const float4* __restrict__ roiList,
    float* __restrict__ pbn, float* __restrict__ pbd, int* __restrict__ pbp)
{
  const int blk  = blockIdx.x;                      // 0..767
  const int bc   = blk >> 5;                        // 0..23
  const int it   = blk & 31;                        // 0..31
  const int b    = bc / 3;
  const int t    = threadIdx.x;
  const int lane = t & 63;
  const int wv   = t >> 6;                          // chunk 0..15, j-ascending

  __shared__ __align__(16) float4 sroi[2048];       // 32 KB
  float* smn = (float*)sroi;                        // [16][64] aliased post-B2
  float* smd = (float*)sroi + 1024;
  int*   smp = (int*)((float*)sroi + 2048);

  const int cnt   = meta[bc];                       // padded mult of 8; 0 if off
  const int obase = bc * PN + (it << 6);            // pb row + i0
  if (cnt == 0) {                                   // inactive label: defaults
    if (t < 64) { pbn[obase + t] = -2.0f; pbd[obase + t] = 1.0f; pbp[obase + t] = 0; }
    return;                                         // == ref masked max = -2
  }

  const float4* src = roiList + bc * CAP;
  for (int idx = t; idx < cnt; idx += 1024)         // coalesced full stage
    sroi[idx] = src[idx];
  const int i = (it << 6) + lane;
  const float4 ri = ((const float4*)rois)[b * PN + i];
  const float areai = (ri.z - ri.x) * (ri.w - ri.y);
  __syncthreads();                                  // B1: staged

  auto upd = [&](float& n, float& d, int& p, const float4 rj, const int pos) {
    const float aj = (rj.z - rj.x) * (rj.w - rj.y); // == sel's expression
    const float lx = fmaxf(ri.x, rj.x), ly = fmaxf(ri.y, rj.y);
    const float rx = fminf(ri.z, rj.z), ry = fminf(ri.w, rj.w);
    const float ww = fmaxf(rx - lx, 0.0f), hh = fmaxf(ry - ly, 0.0f);
    const float inter = ww * hh;
    const float uni   = areai + aj - inter;         // >= 1 always
    if (inter * d > n * uni) { n = inter; d = uni; p = pos; }
  };

  const int C  = (((cnt + 15) >> 4) + 7) & ~7;      // per-chunk span, mult 8
  const int g0 = wv * C;
  int g1 = g0 + C; if (g1 > cnt) g1 = cnt;
  float nA = -2.0f, dA = 1.0f, nB = -2.0f, dB = 1.0f;
  int   pA = 0, pB = 0;
  for (int g = g0; g < g1; g += 4) {                // span mult of 8 -> exact
    const float4 r0 = sroi[g],     r1 = sroi[g + 1];
    const float4 r2 = sroi[g + 2], r3 = sroi[g + 3];
    upd(nA, dA, pA, r0, g);                         // chain A: g, g+1
    upd(nB, dB, pB, r2, g + 2);                     // chain B: g+2, g+3
    upd(nA, dA, pA, r1, g + 1);
    upd(nB, dB, pB, r3, g + 3);
  }
  // merge B into A; exact tie -> lower position (ref = first max)
  const float tB = nB * dA, tA = nA * dB;
  if (tB > tA || (tB == tA && pB < pA)) { nA = nB; dA = dB; pA = pB; }

  __syncthreads();                                  // B2: sroi reads done
  smn[wv * 64 + lane] = nA;
  smd[wv * 64 + lane] = dA;
  smp[wv * 64 + lane] = pA;
  __syncthreads();                                  // B2b: partials visible
  if (wv == 0) {                                    // wave 0 holds chunk 0
    float bn = nA, bd = dA; int bp = pA;
    for (int k = 1; k < NW; ++k) {                  // chunk-ascending: > first
      const float n = smn[k * 64 + lane];
      const float d = smd[k * 64 + lane];
      const int   p = smp[k * 64 + lane];
      if (n * bd > bn * d) { bn = n; bd = d; bp = p; }
    }
    pbn[obase + lane] = bn;                         // coalesced final write
    pbd[obase + lane] = bd;
    pbp[obase + lane] = bp;
  }
}

// ---------------- K3: 3-class merge + epilogue + loss (ticketed finalize) ---
__global__ __launch_bounds__(256) void k_back(
    const float* __restrict__ pbn, const float* __restrict__ pbd,
    const int* __restrict__ pbp, const float* __restrict__ sList,
    const float* __restrict__ logit, const float* __restrict__ labels,
    float* __restrict__ accum, float* __restrict__ loss)
{
  const int t  = threadIdx.x;
  const int gi = blockIdx.x * 256 + t;              // 0..16383
  const int b  = gi >> 11;
  const int i  = gi & (PN - 1);

  float v[3], sc[3];
  #pragma unroll
  for (int c = 0; c < 3; ++c) {
    const int o = (b * 3 + c) * PN + i;
    const float n = pbn[o], d = pbd[o];
    v[c]  = n / d;                                  // exact IEEE divide
    sc[c] = sList[(b * 3 + c) * CAP + pbp[o]];      // dead value if v<=runI
  }
  float runI = -1.0f, runw = 1.0f;
  if (v[0] > runI) { runw = sc[0]; runI = v[0]; }
  if (v[1] > runI) { runw = sc[1]; runI = v[1]; }
  if (v[2] > runI) { runw = sc[2]; runI = v[2]; }
  const float y0 = (v[0] > 0.5f) ? 1.0f : 0.0f;
  const float y1 = (v[1] > 0.5f) ? 1.0f : 0.0f;
  const float y2 = (v[2] > 0.5f) ? 1.0f : 0.0f;
  const float y3 = (y0 + y1 + y2 == 0.0f) ? 1.0f : 0.0f;

  const float4 lg = ((const float4*)logit)[gi];
  const float lb0 = labels[b * 4 + 0];
  const float lb1 = labels[b * 4 + 1];
  const float lb2 = labels[b * 4 + 2];

  auto term = [&](const float l, const float yv, const float labv) -> float {
    const float p  = fminf(fmaxf(l, 1e-7f), 1.0f - 1e-7f);
    const float om = 1.0f - p;
    const float fl = -yv * logf(p) * om * om;       // focal, gamma=2
    const float wl = 10.0f * expf(l) * (1.0f - labv) + labv;
    return runw * fl * wl;                          // /imb deferred
  };
  float s[8];
  s[0] = term(lg.x, y0, lb0); s[1] = term(lg.y, y1, lb1);
  s[2] = term(lg.z, y2, lb2); s[3] = term(lg.w, y3, 1.0f);
  s[4] = y0; s[5] = y1; s[6] = y2; s[7] = y3;

  #pragma unroll
  for (int k = 0; k < 8; ++k)
    #pragma unroll
    for (int off = 32; off; off >>= 1) s[k] += __shfl_xor(s[k], off);

  __shared__ float red[4][8];
  const int wv = t >> 6;
  if ((t & 63) == 0)
    #pragma unroll
    for (int k = 0; k < 8; ++k) red[wv][k] = s[k];
  __syncthreads();
  if (t < 8) {
    const float sum = red[0][t] + red[1][t] + red[2][t] + red[3][t];
    atomicAdd(&accum[t], sum);
  }
  __syncthreads();                                  // block's 8 adds drained
  if (t == 0) {
    __threadfence();
    const int ticket = __hip_atomic_fetch_add((int*)(accum + 8), 1,
                        __ATOMIC_ACQ_REL, __HIP_MEMORY_SCOPE_AGENT);
    if (ticket == 63) {                             // last block finalizes
      float L = 0.0f;
      #pragma unroll
      for (int c = 0; c < 4; ++c) {
        const float num = __hip_atomic_load(accum + c,
                            __ATOMIC_RELAXED, __HIP_MEMORY_SCOPE_AGENT);
        const float den = __hip_atomic_load(accum + 4 + c,
                            __ATOMIC_RELAXED, __HIP_MEMORY_SCOPE_AGENT);
        L += num / (den + 1e-7f);
      }
      loss[0] = L * 0.125f;                         // / bs, exact (pow2)
    }
  }
}

extern "C" void kernel_launch(void* const* d_in, const int* in_sizes, int n_in,
                              void* d_out, int out_size, void* d_ws, size_t ws_size,
                              hipStream_t stream)
{
  (void)in_sizes; (void)n_in; (void)out_size; (void)ws_size;
  const float* inp    = (const float*)d_in[0];
  const float* fcw    = (const float*)d_in[1];
  const float* fcb    = (const float*)d_in[2];
  const float* ps     = (const float*)d_in[3];
  const float* labels = (const float*)d_in[4];
  const float* rois   = (const float*)d_in[5];
  float* out = (float*)d_out;                       // 65536 logit + 1 loss

  char* ws = (char*)d_ws;
  float*  accum   = (float*) (ws);
  int*    meta    = (int*)   (ws + 64);
  float*  sList   = (float*) (ws + 1024);
  float4* roiL    = (float4*)(ws + 394240);
  float*  pbn     = (float*) (ws + 1180672);
  float*  pbd     = (float*) (ws + 1573888);
  int*    pbp     = (int*)   (ws + 1967104);

  k_front <<<1048, 256,  0, stream>>>(inp, fcw, fcb, ps, labels, rois,
                                      out, accum, meta, sList, roiL);
  k_assign<<<768,  1024, 0, stream>>>(rois, meta, roiL, pbn, pbd, pbp);
  k_back  <<<64,   256,  0, stream>>>(pbn, pbd, pbp, sList, out, labels, accum,
                                      out + BSZ * PN * 4);
}